// Round 5
// baseline (544.636 us; speedup 1.0000x reference)
//
#include <hip/hip_runtime.h>
#include <cstdint>

// GCGRU cell, restructured:
//   Zg = [x;h] (1536x4000)  -> Z1 = Zg A^T, Z2 = Z1 A^T      (shared by r,u)
//   gates: r,u = sigmoid(W{f,u} . [Zg;Z1;Z2] + b)            (fp32 conv)
//   rh = r*h (1024x4000)    -> Rh1 = rh A^T, Rh2 = Rh1 A^T
//   cand: c = tanh(Wc . [x,rh, Ax,Arh, A2x,A2rh] + bc);  out = u h + (1-u) c
// Diffusion GEMMs in bf16 MFMA (fp32 accum, split-K); gate/cand convs fp32.
//
// Round-5 change: GEMM K-loop phase-split (T3+T4, m201-style). 4 phases per
// K-tile; each phase = {stage 1 half-tile of t+1 || 4-12 ds_read || 16 MFMA};
// counted waits vmcnt(4)@end-p1, vmcnt(2)@end-p3 (never 0 in loop); raw
// s_barrier only at the 2 wait points. Round-4 profile: 700 TF, MfmaUtil 27%,
// conflicts 0, nothing busy = 2-phase stall (m233).

#define NREAL 4000
#define NPAD  4096

typedef unsigned short u16;
typedef __attribute__((ext_vector_type(8))) short short8;
typedef __attribute__((ext_vector_type(4))) float f32x4;
typedef __attribute__((ext_vector_type(4))) unsigned short u16x4;

__device__ __forceinline__ u16 f2bf(float f) {
  unsigned u = __builtin_bit_cast(unsigned, f);
  return (u16)((u + 0x7FFFu + ((u >> 16) & 1u)) >> 16);
}
__device__ __forceinline__ float bf2f(u16 b) {
  unsigned u = ((unsigned)b) << 16;
  return __builtin_bit_cast(float, u);
}

// ---- adj f32 [4000][4000] -> bf16 [4096][4096], zero-padded ----
__global__ __launch_bounds__(256) void k_pack_adj(const float* __restrict__ adj,
                                                  u16* __restrict__ out) {
  const int idx = blockIdx.x * 256 + threadIdx.x;   // 4096*1024 total
  const int m = idx >> 10;
  const int n0 = (idx & 1023) << 2;
  u16x4 o;
  if (m < NREAL && n0 < NREAL) {   // 4000%4==0 so a float4 never straddles the edge
    const float4 v = *reinterpret_cast<const float4*>(&adj[(long)m * NREAL + n0]);
    o.x = f2bf(v.x); o.y = f2bf(v.y); o.z = f2bf(v.z); o.w = f2bf(v.w);
  } else {
    o.x = 0; o.y = 0; o.z = 0; o.w = 0;
  }
  *reinterpret_cast<u16x4*>(&out[(long)m * NPAD + n0]) = o;
}

// ---- Zg bf16 [1536][4096] = rows (b*96+c): c<32 -> x, else h ----
__global__ __launch_bounds__(256) void k_pack_zg(const float* __restrict__ x,
                                                 const float* __restrict__ h,
                                                 u16* __restrict__ zg) {
  const int idx = blockIdx.x * 256 + threadIdx.x;   // 1536*1024 total
  const int row = idx >> 10;
  const int n0 = (idx & 1023) << 2;
  const int b = row / 96, c = row % 96;
  const float* src = (c < 32) ? &x[((long)b * 32 + c) * NREAL]
                              : &h[((long)b * 64 + (c - 32)) * NREAL];
  u16x4 o;
  if (n0 < NREAL) {
    const float4 v = *reinterpret_cast<const float4*>(&src[n0]);
    o.x = f2bf(v.x); o.y = f2bf(v.y); o.z = f2bf(v.z); o.w = f2bf(v.w);
  } else {
    o.x = 0; o.y = 0; o.z = 0; o.w = 0;
  }
  *reinterpret_cast<u16x4*>(&zg[(long)row * NPAD + n0]) = o;
}

// ---- W transpose pack: Wgt[c][128] = [Wf;Wu]^T, Wct[c][64] = Wc^T ----
__global__ __launch_bounds__(256) void k_pack_w(const float* __restrict__ Wf,
                                                const float* __restrict__ Wu,
                                                const float* __restrict__ Wc,
                                                float* __restrict__ Wgt,
                                                float* __restrict__ Wct) {
  const int idx = blockIdx.x * 256 + threadIdx.x;   // 144 blocks
  if (idx < 288 * 128) {
    const int c = idx >> 7, o = idx & 127;
    Wgt[idx] = (o < 64) ? Wf[o * 288 + c] : Wu[(o - 64) * 288 + c];
  }
  if (idx < 288 * 64) {
    const int c = idx >> 6, o = idx & 63;
    Wct[idx] = Wc[o * 288 + c];
  }
}

#define GLDS(dst, src)                                                         \
  __builtin_amdgcn_global_load_lds(                                            \
      (const __attribute__((address_space(1))) void*)(src),                    \
      (__attribute__((address_space(3))) void*)(dst), 16, 0, 0)

// ---- NT bf16 GEMM, 256x256 tile, BK=64, 8 waves (2M x 4N), dbuf LDS 128KB.
// C[i][m] = sum_n A[i][n]*B[m][n]. 4 phases per K-tile: phase p computes
// mi {2p,2p+1} x ni 0..3 x ks 0..1 (16 MFMA) and stages ONE half-tile of
// K-tile t+1 (p0:B rows0-127, p1:B rows128-255, p2:A rows{0-63,128-191},
// p3:A rows{64-127,192-255}). A-halves = exactly the rows phases 0-1 / 2-3
// read, so stages never race reads. Counted waits: vmcnt(4) end-p1 (retires
// A1(t)), vmcnt(2) end-p3 (retires B0,B1,A0(t+1)); never vmcnt(0) in loop.
// T2 swizzle: 16B slot j of row r holds logical kgrp j^(r&7); staged via
// pre-swizzled global source (linear LDS dst), read via XOR'd byte addr.
template<bool F32OUT>
__global__ __launch_bounds__(512, 2) void k_gemm256(const u16* __restrict__ A,
                                                    const u16* __restrict__ B,
                                                    void* __restrict__ Cout,
                                                    int ktPerChunk, long chunkElems) {
  __shared__ __align__(16) u16 As[2][256 * 64];   // 64 KB
  __shared__ __align__(16) u16 Bs[2][256 * 64];   // 64 KB
  const int tid = threadIdx.x;
  const int lane = tid & 63;
  const int wv = tid >> 6;
  const int wm = wv >> 2;           // 0..1  M-half
  const int wn = wv & 3;            // 0..3  N-quarter

  // staging: thread -> (row tid>>3 within 64-row chunk, 16B slot tid&7);
  // source pre-swizzled so LDS slot s of row r holds kgrp s^(r&7).
  const int srow = tid >> 3;
  const int jlog = (tid & 7) ^ (srow & 7);
  const long kt0 = (long)blockIdx.z * ktPerChunk * 64;
  const u16* aB = A + (long)(blockIdx.y * 256 + srow) * NPAD + kt0 + jlog * 8;
  const u16* bB = B + (long)(blockIdx.x * 256 + srow) * NPAD + kt0 + jlog * 8;
  const int ldst = tid * 8;                      // u16 elems (16B/thread)

  const int fr = lane & 15;
  const int swz = (fr & 7) << 4;                 // row&7 == fr&7 for all frag rows
  const int kb0 = (((lane >> 4) << 4)) ^ swz;    // ks=0 lane byte offset
  const int kb1 = (64 + ((lane >> 4) << 4)) ^ swz;

  f32x4 acc[8][4] = {};
  const int T = ktPerChunk;

  // prologue: all 4 half-tiles of tile 0, full drain (one-time)
  GLDS(&Bs[0][0 + ldst],     bB);
  GLDS(&Bs[0][4096 + ldst],  bB + 64L * NPAD);
  GLDS(&Bs[0][8192 + ldst],  bB + 128L * NPAD);
  GLDS(&Bs[0][12288 + ldst], bB + 192L * NPAD);
  GLDS(&As[0][0 + ldst],     aB);
  GLDS(&As[0][8192 + ldst],  aB + 128L * NPAD);
  GLDS(&As[0][4096 + ldst],  aB + 64L * NPAD);
  GLDS(&As[0][12288 + ldst], aB + 192L * NPAD);
  asm volatile("s_waitcnt vmcnt(0)" ::: "memory");
  __builtin_amdgcn_s_barrier();
  __builtin_amdgcn_sched_barrier(0);

  for (int t = 0; t < T; ++t) {
    const int bsel = t & 1;
    const char* Ab = (const char*)&As[bsel][0];
    const char* Bb = (const char*)&Bs[bsel][0];
    u16* An = &As[bsel ^ 1][0];
    u16* Bn = &Bs[bsel ^ 1][0];
    const bool more = (t + 1 < T);
    const long ko = (long)(t + 1) * 64;
    short8 bv[4][2];
#pragma unroll
    for (int p = 0; p < 4; ++p) {
      // stage one half-tile of t+1 (order pinned by per-phase fence)
      if (more) {
        if (p == 0) { GLDS(Bn + ldst, bB + ko);
                      GLDS(Bn + 4096 + ldst, bB + 64L * NPAD + ko); }
        if (p == 1) { GLDS(Bn + 8192 + ldst, bB + 128L * NPAD + ko);
                      GLDS(Bn + 12288 + ldst, bB + 192L * NPAD + ko); }
        if (p == 2) { GLDS(An + ldst, aB + ko);
                      GLDS(An + 8192 + ldst, aB + 128L * NPAD + ko); }
        if (p == 3) { GLDS(An + 4096 + ldst, aB + 64L * NPAD + ko);
                      GLDS(An + 12288 + ldst, aB + 192L * NPAD + ko); }
      }
      asm volatile("" ::: "memory");   // pin stage-issue order (vmcnt math)
      // ds reads for this phase's MFMAs
      if (p == 0) {
#pragma unroll
        for (int ni = 0; ni < 4; ++ni) {
          const int brow = (wn << 6) + (ni << 4) + fr;
          bv[ni][0] = *(const short8*)(Bb + brow * 128 + kb0);
          bv[ni][1] = *(const short8*)(Bb + brow * 128 + kb1);
        }
      }
      short8 av[2][2];
#pragma unroll
      for (int q = 0; q < 2; ++q) {
        const int arow = (wm << 7) + ((2 * p + q) << 4) + fr;
        av[q][0] = *(const short8*)(Ab + arow * 128 + kb0);
        av[q][1] = *(const short8*)(Ab + arow * 128 + kb1);
      }
      __builtin_amdgcn_s_setprio(1);
#pragma unroll
      for (int q = 0; q < 2; ++q)
#pragma unroll
        for (int ni = 0; ni < 4; ++ni) {
          acc[2 * p + q][ni] = __builtin_amdgcn_mfma_f32_16x16x32_bf16(
              av[q][0], bv[ni][0], acc[2 * p + q][ni], 0, 0, 0);
          acc[2 * p + q][ni] = __builtin_amdgcn_mfma_f32_16x16x32_bf16(
              av[q][1], bv[ni][1], acc[2 * p + q][ni], 0, 0, 0);
        }
      __builtin_amdgcn_s_setprio(0);
      if (p == 1) {                      // A1(t) must be landed for p2-p3
        if (more) asm volatile("s_waitcnt vmcnt(4)" ::: "memory");
        else      asm volatile("s_waitcnt vmcnt(0)" ::: "memory");
        __builtin_amdgcn_s_barrier();
        __builtin_amdgcn_sched_barrier(0);
      }
      if (p == 3 && more) {              // B0,B1,A0(t+1) landed; A1(t+1) in flight
        asm volatile("s_waitcnt vmcnt(2)" ::: "memory");
        __builtin_amdgcn_s_barrier();
        __builtin_amdgcn_sched_barrier(0);
      }
    }
  }

  // C/D layout (m89-verified): col = lane&15, row = (lane>>4)*4 + q
  const int rb = blockIdx.y * 256 + (wm << 7) + ((lane >> 4) << 2);
  const int cb = blockIdx.x * 256 + (wn << 6) + fr;
  if (F32OUT) {
    float* C = (float*)Cout + (long)blockIdx.z * chunkElems;
#pragma unroll
    for (int mi = 0; mi < 8; ++mi)
#pragma unroll
      for (int ni = 0; ni < 4; ++ni)
#pragma unroll
        for (int q = 0; q < 4; ++q)
          C[(long)(rb + (mi << 4) + q) * NPAD + cb + (ni << 4)] = acc[mi][ni][q];
  } else {
    u16* C = (u16*)Cout;
#pragma unroll
    for (int mi = 0; mi < 8; ++mi)
#pragma unroll
      for (int ni = 0; ni < 4; ++ni)
#pragma unroll
        for (int q = 0; q < 4; ++q)
          C[(long)(rb + (mi << 4) + q) * NPAD + cb + (ni << 4)] = f2bf(acc[mi][ni][q]);
  }
}

// ---- sum NC fp32 partial chunks -> bf16 ----
template<int NC>
__global__ __launch_bounds__(256) void k_combine(const float* __restrict__ P,
                                                 long chunkElems,
                                                 u16* __restrict__ out) {
  const long i4 = ((long)blockIdx.x * 256 + threadIdx.x) * 4;
  f32x4 s = *reinterpret_cast<const f32x4*>(&P[i4]);
#pragma unroll
  for (int c = 1; c < NC; ++c) {
    const f32x4 v = *reinterpret_cast<const f32x4*>(&P[(long)c * chunkElems + i4]);
    s.x += v.x; s.y += v.y; s.z += v.z; s.w += v.w;
  }
  u16x4 o;
  o.x = f2bf(s.x); o.y = f2bf(s.y); o.z = f2bf(s.z); o.w = f2bf(s.w);
  *reinterpret_cast<u16x4*>(&out[i4]) = o;
}

// ---- gates: r,u = sigmoid(Wgt^T.[z;z1;z2]+b); emit rh(bf16 [+f32]), u(f32) ----
__global__ __launch_bounds__(512) void k_gates(
    const float* __restrict__ x, const float* __restrict__ h,
    const float* __restrict__ Wgt,
    const float* __restrict__ bfv, const float* __restrict__ buv,
    const u16* __restrict__ Z1, const u16* __restrict__ Z2,
    u16* __restrict__ rh_bf, float* __restrict__ rh_f, float* __restrict__ u_f) {
  const int lane = threadIdx.x & 63;
  const int wq = __builtin_amdgcn_readfirstlane(threadIdx.x >> 6);  // 0..7
  const int b = blockIdx.y;
  const int n0 = blockIdx.x * 128 + (lane << 1);
  if (n0 >= NREAL) return;
  const int ob = wq << 4;                       // 16 outputs, combined index
  const float* xb = x + (long)b * 32 * NREAL + n0;
  const float* hb = h + (long)b * 64 * NREAL + n0;
  const u16* z1b = Z1 + (long)b * 96 * NPAD + n0;
  const u16* z2b = Z2 + (long)b * 96 * NPAD + n0;

  float a0[16] = {}, a1[16] = {};
#pragma unroll 4
  for (int c = 0; c < 32; ++c) {                // order-0: x
    const float2 f = *reinterpret_cast<const float2*>(&xb[(long)c * NREAL]);
#pragma unroll
    for (int oi = 0; oi < 16; ++oi) {
      const float w = Wgt[c * 128 + ob + oi];
      a0[oi] = fmaf(w, f.x, a0[oi]); a1[oi] = fmaf(w, f.y, a1[oi]);
    }
  }
#pragma unroll 4
  for (int c = 0; c < 64; ++c) {                // order-0: h
    const float2 f = *reinterpret_cast<const float2*>(&hb[(long)c * NREAL]);
#pragma unroll
    for (int oi = 0; oi < 16; ++oi) {
      const float w = Wgt[(32 + c) * 128 + ob + oi];
      a0[oi] = fmaf(w, f.x, a0[oi]); a1[oi] = fmaf(w, f.y, a1[oi]);
    }
  }
#pragma unroll 4
  for (int c = 0; c < 96; ++c) {                // order-1
    const unsigned pv = *reinterpret_cast<const unsigned*>(&z1b[(long)c * NPAD]);
    const float f0 = bf2f((u16)(pv & 0xffff)), f1 = bf2f((u16)(pv >> 16));
#pragma unroll
    for (int oi = 0; oi < 16; ++oi) {
      const float w = Wgt[(96 + c) * 128 + ob + oi];
      a0[oi] = fmaf(w, f0, a0[oi]); a1[oi] = fmaf(w, f1, a1[oi]);
    }
  }
#pragma unroll 4
  for (int c = 0; c < 96; ++c) {                // order-2
    const unsigned pv = *reinterpret_cast<const unsigned*>(&z2b[(long)c * NPAD]);
    const float f0 = bf2f((u16)(pv & 0xffff)), f1 = bf2f((u16)(pv >> 16));
#pragma unroll
    for (int oi = 0; oi < 16; ++oi) {
      const float w = Wgt[(192 + c) * 128 + ob + oi];
      a0[oi] = fmaf(w, f0, a0[oi]); a1[oi] = fmaf(w, f1, a1[oi]);
    }
  }

  if (wq < 4) {                                 // r outputs -> rh
#pragma unroll
    for (int oi = 0; oi < 16; ++oi) {
      const int og = ob + oi;
      const float bb = bfv[og];
      const float r0 = 1.f / (1.f + __expf(-(a0[oi] + bb)));
      const float r1 = 1.f / (1.f + __expf(-(a1[oi] + bb)));
      const float2 hv = *reinterpret_cast<const float2*>(&hb[(long)og * NREAL]);
      const float rh0 = r0 * hv.x, rh1 = r1 * hv.y;
      if (rh_f)
        *reinterpret_cast<float2*>(&rh_f[((long)b * 64 + og) * NREAL + n0]) =
            make_float2(rh0, rh1);
      const unsigned pk = (unsigned)f2bf(rh0) | ((unsigned)f2bf(rh1) << 16);
      *reinterpret_cast<unsigned*>(&rh_bf[((long)b * 64 + og) * NPAD + n0]) = pk;
    }
  } else {                                      // u outputs
#pragma unroll
    for (int oi = 0; oi < 16; ++oi) {
      const int og = (ob - 64) + oi;
      const float bb = buv[og];
      const float u0 = 1.f / (1.f + __expf(-(a0[oi] + bb)));
      const float u1 = 1.f / (1.f + __expf(-(a1[oi] + bb)));
      *reinterpret_cast<float2*>(&u_f[((long)b * 64 + og) * NREAL + n0]) =
          make_float2(u0, u1);
    }
  }
}

// ---- candidate + output: c = tanh(Wct^T.feats+bc); out = u h + (1-u) c ----
template<bool RHF32>
__global__ __launch_bounds__(512) void k_cand(
    const float* __restrict__ x, const float* __restrict__ h,
    const float* __restrict__ Wct, const float* __restrict__ bcv,
    const u16* __restrict__ Z1, const u16* __restrict__ Z2,
    const u16* __restrict__ Rhb, const u16* __restrict__ Rh1,
    const u16* __restrict__ Rh2,
    const float* __restrict__ rh_f, const float* __restrict__ u_f,
    float* __restrict__ out) {
  const int lane = threadIdx.x & 63;
  const int wq = __builtin_amdgcn_readfirstlane(threadIdx.x >> 6);  // 0..7
  const int ob = (wq & 3) << 4;                 // 16 outputs
  const int n = blockIdx.x * 128 + ((wq >> 2) << 6) + lane;
  const int b = blockIdx.y;
  if (n >= NREAL) return;
  const float* xb = x + (long)b * 32 * NREAL + n;
  const float* hb = h + (long)b * 64 * NREAL + n;
  const u16* z1b = Z1 + (long)b * 96 * NPAD + n;
  const u16* z2b = Z2 + (long)b * 96 * NPAD + n;
  const u16* r1b = Rh1 + (long)b * 64 * NPAD + n;
  const u16* r2b = Rh2 + (long)b * 64 * NPAD + n;
  const float* rfb = rh_f + (long)b * 64 * NREAL + n;
  const u16* rbb = Rhb + (long)b * 64 * NPAD + n;

  float acc[16] = {};
#pragma unroll 4
  for (int c = 0; c < 32; ++c) {                // x
    const float f = xb[(long)c * NREAL];
#pragma unroll
    for (int oi = 0; oi < 16; ++oi)
      acc[oi] = fmaf(Wct[c * 64 + ob + oi], f, acc[oi]);
  }
#pragma unroll 4
  for (int c = 0; c < 64; ++c) {                // rh
    const float f = RHF32 ? rfb[(long)c * NREAL] : bf2f(rbb[(long)c * NPAD]);
#pragma unroll
    for (int oi = 0; oi < 16; ++oi)
      acc[oi] = fmaf(Wct[(32 + c) * 64 + ob + oi], f, acc[oi]);
  }
#pragma unroll 4
  for (int c = 0; c < 32; ++c) {                // A x (Z1 x-part)
    const float f = bf2f(z1b[(long)c * NPAD]);
#pragma unroll
    for (int oi = 0; oi < 16; ++oi)
      acc[oi] = fmaf(Wct[(96 + c) * 64 + ob + oi], f, acc[oi]);
  }
#pragma unroll 4
  for (int c = 0; c < 64; ++c) {                // A rh
    const float f = bf2f(r1b[(long)c * NPAD]);
#pragma unroll
    for (int oi = 0; oi < 16; ++oi)
      acc[oi] = fmaf(Wct[(128 + c) * 64 + ob + oi], f, acc[oi]);
  }
#pragma unroll 4
  for (int c = 0; c < 32; ++c) {                // A^2 x (Z2 x-part)
    const float f = bf2f(z2b[(long)c * NPAD]);
#pragma unroll
    for (int oi = 0; oi < 16; ++oi)
      acc[oi] = fmaf(Wct[(192 + c) * 64 + ob + oi], f, acc[oi]);
  }
#pragma unroll 4
  for (int c = 0; c < 64; ++c) {                // A^2 rh
    const float f = bf2f(r2b[(long)c * NPAD]);
#pragma unroll
    for (int oi = 0; oi < 16; ++oi)
      acc[oi] = fmaf(Wct[(224 + c) * 64 + ob + oi], f, acc[oi]);
  }

#pragma unroll
  for (int oi = 0; oi < 16; ++oi) {
    const int og = ob + oi;
    float v = acc[oi] + bcv[og];
    v = fminf(fmaxf(v, -15.f), 15.f);
    const float e2 = __expf(2.f * v);
    const float cv = (e2 - 1.f) / (e2 + 1.f);
    const float u = u_f[((long)b * 64 + og) * NREAL + n];
    out[((long)b * 64 + og) * NREAL + n] = u * hb[(long)og * NREAL] + (1.f - u) * cv;
  }
}

extern "C" void kernel_launch(void* const* d_in, const int* in_sizes, int n_in,
                              void* d_out, int out_size, void* d_ws, size_t ws_size,
                              hipStream_t stream) {
  const float* x   = (const float*)d_in[0];
  const float* h   = (const float*)d_in[1];
  const float* adj = (const float*)d_in[2];
  const float* Wf  = (const float*)d_in[3];
  const float* bf_ = (const float*)d_in[4];
  const float* Wu  = (const float*)d_in[5];
  const float* bu_ = (const float*)d_in[6];
  const float* Wc  = (const float*)d_in[7];
  const float* bc_ = (const float*)d_in[8];
  float* out = (float*)d_out;

  char* p = (char*)d_ws;
  auto alloc = [&](size_t bytes) { char* r = p; p += bytes; return r; };
  u16* adjb = (u16*)alloc((size_t)NPAD * NPAD * 2);       // 33.55 MB
  u16* Zg   = (u16*)alloc((size_t)1536 * NPAD * 2);       // 12.58 MB (Rhb aliases)
  u16* Rhb  = Zg;
  u16* Z1   = (u16*)alloc((size_t)1536 * NPAD * 2);
  u16* Z2   = (u16*)alloc((size_t)1536 * NPAD * 2);
  u16* Rh1  = (u16*)alloc((size_t)1024 * NPAD * 2);       // 8.39 MB
  u16* Rh2  = (u16*)alloc((size_t)1024 * NPAD * 2);
  float* uf = (float*)alloc((size_t)16 * 64 * NREAL * 4); // 16.38 MB
  float* Wgt = (float*)alloc(288 * 128 * 4);              // 147 KB
  float* Wct = (float*)alloc(288 * 64 * 4);               // 74 KB
  const size_t RHFB = (size_t)16 * 64 * NREAL * 4;
  size_t used = (size_t)(p - (char*)d_ws);
  float* rhf = nullptr;
  if (ws_size >= used + RHFB) rhf = (float*)alloc(RHFB);
  used = (size_t)(p - (char*)d_ws);

  // split-K partial buffer: sized for the largest config in use
  const size_t PZ2 = (size_t)2 * 1536 * NPAD * 4;         // 50.33 MB
  const size_t PR4 = (size_t)4 * 1024 * NPAD * 4;         // 67.11 MB
  int sZ = 1, sR = 1;
  float* P = nullptr;
  if (ws_size >= used + PR4)      { P = (float*)alloc(PR4); sZ = 2; sR = 4; }
  else if (ws_size >= used + PZ2) { P = (float*)alloc(PZ2); sZ = 2; sR = 2; }

  auto gemm = [&](const u16* Ax, const u16* Bx, u16* Cb, int M, int sk) {
    const long ce = (long)M * NPAD;
    const int mt = M / 256;
    const int kpc = 64 / sk;       // K-tiles (of 64) per chunk
    if (sk == 4) {
      k_gemm256<true><<<dim3(16, mt, 4), 512, 0, stream>>>(Ax, Bx, P, kpc, ce);
      k_combine<4><<<dim3(M * 4), 256, 0, stream>>>(P, ce, Cb);
    } else if (sk == 2) {
      k_gemm256<true><<<dim3(16, mt, 2), 512, 0, stream>>>(Ax, Bx, P, kpc, ce);
      k_combine<2><<<dim3(M * 4), 256, 0, stream>>>(P, ce, Cb);
    } else {
      k_gemm256<false><<<dim3(16, mt, 1), 512, 0, stream>>>(Ax, Bx, Cb, 64, ce);
    }
  };

  k_pack_adj<<<dim3(NPAD * (NPAD / 4) / 256), 256, 0, stream>>>(adj, adjb);
  k_pack_zg <<<dim3(1536 * (NPAD / 4) / 256), 256, 0, stream>>>(x, h, Zg);
  k_pack_w  <<<dim3(144), 256, 0, stream>>>(Wf, Wu, Wc, Wgt, Wct);
  gemm(Zg, adjb, Z1, 1536, sZ);                               // Z1 = Zg A^T
  gemm(Z1, adjb, Z2, 1536, sZ);                               // Z2 = Z1 A^T
  k_gates<<<dim3(32, 16), 512, 0, stream>>>(x, h, Wgt, bf_, bu_, Z1, Z2,
                                            Rhb, rhf, uf);
  gemm(Rhb, adjb, Rh1, 1024, sR);                             // Rh1 = rh A^T
  gemm(Rh1, adjb, Rh2, 1024, sR);                             // Rh2 = Rh1 A^T
  if (rhf)
    k_cand<true><<<dim3(32, 16), 512, 0, stream>>>(x, h, Wct, bc_, Z1, Z2, Rhb,
                                                   Rh1, Rh2, rhf, uf, out);
  else
    k_cand<false><<<dim3(32, 16), 512, 0, stream>>>(x, h, Wct, bc_, Z1, Z2, Rhb,
                                                    Rh1, Rh2, rhf, uf, out);
}

// Round 6
// 482.539 us; speedup vs baseline: 1.1287x; 1.1287x over previous
//
#include <hip/hip_runtime.h>
#include <cstdint>

// GCGRU cell, restructured:
//   Zg = [x;h] (1536x4000)  -> Z1 = Zg A^T, Z2 = Z1 A^T      (shared by r,u)
//   gates: r,u = sigmoid(W{f,u} . [Zg;Z1;Z2] + b)            (fp32 conv)
//   rh = r*h (1024x4000)    -> Rh1 = rh A^T, Rh2 = Rh1 A^T
//   cand: c = tanh(Wc . [x,rh, Ax,Arh, A2x,A2rh] + bc);  out = u h + (1-u) c
//
// Round-6: A/B within one bench.
//   Z-GEMMs  -> k_gemm8p : m201-faithful dual-barrier phase skeleton
//               {ds_read; stage; [lgkmcnt(8)]; s_barrier; lgkmcnt(0);
//                sched_barrier; setprio1; 16 MFMA; setprio0; s_barrier}
//               x4 phases/K-tile; counted vmcnt(4)@p1 / vmcnt(2)@p3 (never 0).
//   Rh-GEMMs -> k_gemm256 : round-4 2-phase version (known 696 TF baseline).
// Round-5 lesson: same waits/stages with raw dep + "memory" fences REGRESSED
// (88us, MfmaUtil 21%) - the per-phase barrier pattern is the lever, not the
// vmcnt counting alone.

#define NREAL 4000
#define NPAD  4096

typedef unsigned short u16;
typedef __attribute__((ext_vector_type(8))) short short8;
typedef __attribute__((ext_vector_type(4))) float f32x4;
typedef __attribute__((ext_vector_type(4))) unsigned short u16x4;

__device__ __forceinline__ u16 f2bf(float f) {
  unsigned u = __builtin_bit_cast(unsigned, f);
  return (u16)((u + 0x7FFFu + ((u >> 16) & 1u)) >> 16);
}
__device__ __forceinline__ float bf2f(u16 b) {
  unsigned u = ((unsigned)b) << 16;
  return __builtin_bit_cast(float, u);
}

// ---- adj f32 [4000][4000] -> bf16 [4096][4096], zero-padded ----
__global__ __launch_bounds__(256) void k_pack_adj(const float* __restrict__ adj,
                                                  u16* __restrict__ out) {
  const int idx = blockIdx.x * 256 + threadIdx.x;
  const int m = idx >> 10;
  const int n0 = (idx & 1023) << 2;
  u16x4 o;
  if (m < NREAL && n0 < NREAL) {
    const float4 v = *reinterpret_cast<const float4*>(&adj[(long)m * NREAL + n0]);
    o.x = f2bf(v.x); o.y = f2bf(v.y); o.z = f2bf(v.z); o.w = f2bf(v.w);
  } else {
    o.x = 0; o.y = 0; o.z = 0; o.w = 0;
  }
  *reinterpret_cast<u16x4*>(&out[(long)m * NPAD + n0]) = o;
}

// ---- Zg bf16 [1536][4096] = rows (b*96+c): c<32 -> x, else h ----
__global__ __launch_bounds__(256) void k_pack_zg(const float* __restrict__ x,
                                                 const float* __restrict__ h,
                                                 u16* __restrict__ zg) {
  const int idx = blockIdx.x * 256 + threadIdx.x;
  const int row = idx >> 10;
  const int n0 = (idx & 1023) << 2;
  const int b = row / 96, c = row % 96;
  const float* src = (c < 32) ? &x[((long)b * 32 + c) * NREAL]
                              : &h[((long)b * 64 + (c - 32)) * NREAL];
  u16x4 o;
  if (n0 < NREAL) {
    const float4 v = *reinterpret_cast<const float4*>(&src[n0]);
    o.x = f2bf(v.x); o.y = f2bf(v.y); o.z = f2bf(v.z); o.w = f2bf(v.w);
  } else {
    o.x = 0; o.y = 0; o.z = 0; o.w = 0;
  }
  *reinterpret_cast<u16x4*>(&zg[(long)row * NPAD + n0]) = o;
}

// ---- W transpose pack: Wgt[c][128] = [Wf;Wu]^T, Wct[c][64] = Wc^T ----
__global__ __launch_bounds__(256) void k_pack_w(const float* __restrict__ Wf,
                                                const float* __restrict__ Wu,
                                                const float* __restrict__ Wc,
                                                float* __restrict__ Wgt,
                                                float* __restrict__ Wct) {
  const int idx = blockIdx.x * 256 + threadIdx.x;
  if (idx < 288 * 128) {
    const int c = idx >> 7, o = idx & 127;
    Wgt[idx] = (o < 64) ? Wf[o * 288 + c] : Wu[(o - 64) * 288 + c];
  }
  if (idx < 288 * 64) {
    const int c = idx >> 6, o = idx & 63;
    Wct[idx] = Wc[o * 288 + c];
  }
}

#define GLDS(dst, src)                                                         \
  __builtin_amdgcn_global_load_lds(                                            \
      (const __attribute__((address_space(1))) void*)(src),                    \
      (__attribute__((address_space(3))) void*)(dst), 16, 0, 0)

// ---- NT bf16 GEMM, 256x256/BK=64/8-wave, m201-faithful 4-phase skeleton ----
// Phase p: MFMA quadrant mi{2p,2p+1}x4ni x K=64. Stage plan (tile t+1 into
// buf^1): p0:B rows0-127, p1:B rows128-255, p2:A chunks{0-63,128-191},
// p3:A chunks{64-127,192-255}. Waits: vmcnt(4)@p1 end (retires A-chunks of t),
// vmcnt(2)@p3 end (retires B+A02 of t+1). T2 swizzle: slot s of row r holds
// kgrp s^(r&7); staged via pre-swizzled global source, read via XOR'd addr.
template<bool F32OUT>
__global__ __launch_bounds__(512) void k_gemm8p(const u16* __restrict__ A,
                                                const u16* __restrict__ B,
                                                void* __restrict__ Cout,
                                                int ktPerChunk, long chunkElems) {
  __shared__ __align__(16) u16 As[2][256 * 64];
  __shared__ __align__(16) u16 Bs[2][256 * 64];
  const int tid = threadIdx.x;
  const int lane = tid & 63;
  const int wv = tid >> 6;
  const int wm = wv >> 2;           // 0..1  M-half
  const int wn = wv & 3;            // 0..3  N-quarter

  const int srow = tid >> 3;
  const int jlog = (tid & 7) ^ (srow & 7);
  const long kt0 = (long)blockIdx.z * ktPerChunk * 64;
  const u16* aB = A + (long)(blockIdx.y * 256 + srow) * NPAD + kt0 + jlog * 8;
  const u16* bB = B + (long)(blockIdx.x * 256 + srow) * NPAD + kt0 + jlog * 8;
  const int ldst = tid * 8;

  const int fr = lane & 15;
  const int swz = (fr & 7) << 4;
  const int kb0 = (((lane >> 4) << 4)) ^ swz;
  const int kb1 = (64 + ((lane >> 4) << 4)) ^ swz;

  f32x4 acc[8][4] = {};
  const int T = ktPerChunk;

  // prologue: tile 0 fully staged, one-time full drain
  GLDS(&Bs[0][0 + ldst],     bB);
  GLDS(&Bs[0][4096 + ldst],  bB + 64L * NPAD);
  GLDS(&Bs[0][8192 + ldst],  bB + 128L * NPAD);
  GLDS(&Bs[0][12288 + ldst], bB + 192L * NPAD);
  GLDS(&As[0][0 + ldst],     aB);
  GLDS(&As[0][8192 + ldst],  aB + 128L * NPAD);
  GLDS(&As[0][4096 + ldst],  aB + 64L * NPAD);
  GLDS(&As[0][12288 + ldst], aB + 192L * NPAD);
  asm volatile("s_waitcnt vmcnt(0)" ::: "memory");
  __builtin_amdgcn_s_barrier();

  for (int t = 0; t < T; ++t) {
    const int bs = t & 1;
    const char* Ab = (const char*)&As[bs][0];
    const char* Bb = (const char*)&Bs[bs][0];
    u16* An = &As[bs ^ 1][0];
    u16* Bn = &Bs[bs ^ 1][0];
    const bool more = (t + 1 < T);
    const long ko = (long)(t + 1) * 64;
    short8 bv[4][2];
#pragma unroll
    for (int p = 0; p < 4; ++p) {
      // --- ds-load register subtile ---
      if (p == 0) {
#pragma unroll
        for (int ni = 0; ni < 4; ++ni) {
          const int brow = (wn << 6) + (ni << 4) + fr;
          bv[ni][0] = *(const short8*)(Bb + brow * 128 + kb0);
          bv[ni][1] = *(const short8*)(Bb + brow * 128 + kb1);
        }
      }
      short8 av[2][2];
#pragma unroll
      for (int q = 0; q < 2; ++q) {
        const int arow = (wm << 7) + ((2 * p + q) << 4) + fr;
        av[q][0] = *(const short8*)(Ab + arow * 128 + kb0);
        av[q][1] = *(const short8*)(Ab + arow * 128 + kb1);
      }
      // --- stage 1 half-tile of t+1 ---
      if (more) {
        if (p == 0) { GLDS(Bn + ldst, bB + ko);
                      GLDS(Bn + 4096 + ldst, bB + 64L * NPAD + ko); }
        if (p == 1) { GLDS(Bn + 8192 + ldst, bB + 128L * NPAD + ko);
                      GLDS(Bn + 12288 + ldst, bB + 192L * NPAD + ko); }
        if (p == 2) { GLDS(An + ldst, aB + ko);
                      GLDS(An + 8192 + ldst, aB + 128L * NPAD + ko); }
        if (p == 3) { GLDS(An + 4096 + ldst, aB + 64L * NPAD + ko);
                      GLDS(An + 12288 + ldst, aB + 192L * NPAD + ko); }
      }
      if (p == 0) asm volatile("s_waitcnt lgkmcnt(8)" ::: "memory");
      __builtin_amdgcn_s_barrier();
      asm volatile("s_waitcnt lgkmcnt(0)" ::: "memory");
      __builtin_amdgcn_sched_barrier(0);     // rule 18: pin MFMA below the wait
      __builtin_amdgcn_s_setprio(1);
#pragma unroll
      for (int q = 0; q < 2; ++q)
#pragma unroll
        for (int ni = 0; ni < 4; ++ni) {
          acc[2 * p + q][ni] = __builtin_amdgcn_mfma_f32_16x16x32_bf16(
              av[q][0], bv[ni][0], acc[2 * p + q][ni], 0, 0, 0);
          acc[2 * p + q][ni] = __builtin_amdgcn_mfma_f32_16x16x32_bf16(
              av[q][1], bv[ni][1], acc[2 * p + q][ni], 0, 0, 0);
        }
      __builtin_amdgcn_s_setprio(0);
      if (p == 1) {                  // A-chunks{1,3}(t) must land for p2/p3
        if (more) asm volatile("s_waitcnt vmcnt(4)" ::: "memory");
        else      asm volatile("s_waitcnt vmcnt(0)" ::: "memory");
      }
      if (p == 3 && more)            // B(t+1)+A02(t+1) landed; A13(t+1) flies
        asm volatile("s_waitcnt vmcnt(2)" ::: "memory");
      __builtin_amdgcn_s_barrier();
    }
  }

  // C/D layout (m89-verified): col = lane&15, row = (lane>>4)*4 + q
  const int rb = blockIdx.y * 256 + (wm << 7) + ((lane >> 4) << 2);
  const int cb = blockIdx.x * 256 + (wn << 6) + fr;
  if (F32OUT) {
    float* C = (float*)Cout + (long)blockIdx.z * chunkElems;
#pragma unroll
    for (int mi = 0; mi < 8; ++mi)
#pragma unroll
      for (int ni = 0; ni < 4; ++ni)
#pragma unroll
        for (int q = 0; q < 4; ++q)
          C[(long)(rb + (mi << 4) + q) * NPAD + cb + (ni << 4)] = acc[mi][ni][q];
  } else {
    u16* C = (u16*)Cout;
#pragma unroll
    for (int mi = 0; mi < 8; ++mi)
#pragma unroll
      for (int ni = 0; ni < 4; ++ni)
#pragma unroll
        for (int q = 0; q < 4; ++q)
          C[(long)(rb + (mi << 4) + q) * NPAD + cb + (ni << 4)] = f2bf(acc[mi][ni][q]);
  }
}

// ---- round-4 2-phase GEMM (known-good baseline) — used for Rh GEMMs ----
template<bool F32OUT>
__global__ __launch_bounds__(512, 2) void k_gemm256(const u16* __restrict__ A,
                                                    const u16* __restrict__ B,
                                                    void* __restrict__ Cout,
                                                    int ktPerChunk, long chunkElems) {
  __shared__ __align__(16) u16 As[2][256 * 64];
  __shared__ __align__(16) u16 Bs[2][256 * 64];
  const int tid = threadIdx.x;
  const int lane = tid & 63;
  const int wv = tid >> 6;
  const int wm = wv >> 2;
  const int wn = wv & 3;
  const int bm = blockIdx.y, bn = blockIdx.x;

  const int srow = tid >> 3;
  const int jlog = (tid & 7) ^ (srow & 7);
  const long kt0 = (long)blockIdx.z * ktPerChunk * 64;
  const u16* aS = A + (long)(bm * 256 + srow) * NPAD + kt0 + jlog * 8;
  const u16* bS = B + (long)(bn * 256 + srow) * NPAD + kt0 + jlog * 8;
  const int ldst = tid * 8;

  const int fr = lane & 15;
  const int swz = (fr & 7) << 4;
  const int kb0 = (((lane >> 4) << 4)) ^ swz;
  const int kb1 = (64 + ((lane >> 4) << 4)) ^ swz;

  f32x4 acc[8][4] = {};

#define STAGE2(buf, kk)                                                        \
  {                                                                            \
    const long ko2 = (long)(kk) * 64;                                          \
    _Pragma("unroll")                                                          \
    for (int i = 0; i < 4; ++i)                                                \
      GLDS(&As[buf][i * 4096 + ldst], aS + (long)i * 64 * NPAD + ko2);         \
    _Pragma("unroll")                                                          \
    for (int i = 0; i < 4; ++i)                                                \
      GLDS(&Bs[buf][i * 4096 + ldst], bS + (long)i * 64 * NPAD + ko2);         \
  }

  STAGE2(0, 0)
  int cur = 0;
  for (int kk = 0; kk < ktPerChunk; ++kk) {
    if (kk + 1 < ktPerChunk) {
      STAGE2(cur ^ 1, kk + 1)
      asm volatile("s_waitcnt vmcnt(8)\ns_barrier" ::: "memory");
    } else {
      asm volatile("s_waitcnt vmcnt(0)\ns_barrier" ::: "memory");
    }
    const char* Ab = (const char*)&As[cur][0];
    const char* Bb = (const char*)&Bs[cur][0];
#pragma unroll
    for (int ks = 0; ks < 2; ++ks) {
      const int k2 = (ks == 0) ? 0 : 64;
      short8 av[8], bv[4];
#pragma unroll
      for (int mi = 0; mi < 8; ++mi) {
        const int row = (wm << 7) + (mi << 4) + fr;
        av[mi] = *(const short8*)(Ab + row * 128 +
                                  ((k2 + ((lane >> 4) << 4)) ^ ((row & 7) << 4)));
      }
#pragma unroll
      for (int ni = 0; ni < 4; ++ni) {
        const int row = (wn << 6) + (ni << 4) + fr;
        bv[ni] = *(const short8*)(Bb + row * 128 +
                                  ((k2 + ((lane >> 4) << 4)) ^ ((row & 7) << 4)));
      }
      __builtin_amdgcn_s_setprio(1);
#pragma unroll
      for (int mi = 0; mi < 8; ++mi)
#pragma unroll
        for (int ni = 0; ni < 4; ++ni)
          acc[mi][ni] = __builtin_amdgcn_mfma_f32_16x16x32_bf16(av[mi], bv[ni],
                                                                acc[mi][ni], 0, 0, 0);
      __builtin_amdgcn_s_setprio(0);
    }
    asm volatile("s_barrier" ::: "memory");
    cur ^= 1;
  }
#undef STAGE2

  const int rb = bm * 256 + (wm << 7) + ((lane >> 4) << 2);
  const int cb = bn * 256 + (wn << 6) + fr;
  if (F32OUT) {
    float* C = (float*)Cout + (long)blockIdx.z * chunkElems;
#pragma unroll
    for (int mi = 0; mi < 8; ++mi)
#pragma unroll
      for (int ni = 0; ni < 4; ++ni)
#pragma unroll
        for (int q = 0; q < 4; ++q)
          C[(long)(rb + (mi << 4) + q) * NPAD + cb + (ni << 4)] = acc[mi][ni][q];
  } else {
    u16* C = (u16*)Cout;
#pragma unroll
    for (int mi = 0; mi < 8; ++mi)
#pragma unroll
      for (int ni = 0; ni < 4; ++ni)
#pragma unroll
        for (int q = 0; q < 4; ++q)
          C[(long)(rb + (mi << 4) + q) * NPAD + cb + (ni << 4)] = f2bf(acc[mi][ni][q]);
  }
}

// ---- sum NC fp32 partial chunks -> bf16 ----
template<int NC>
__global__ __launch_bounds__(256) void k_combine(const float* __restrict__ P,
                                                 long chunkElems,
                                                 u16* __restrict__ out) {
  const long i4 = ((long)blockIdx.x * 256 + threadIdx.x) * 4;
  f32x4 s = *reinterpret_cast<const f32x4*>(&P[i4]);
#pragma unroll
  for (int c = 1; c < NC; ++c) {
    const f32x4 v = *reinterpret_cast<const f32x4*>(&P[(long)c * chunkElems + i4]);
    s.x += v.x; s.y += v.y; s.z += v.z; s.w += v.w;
  }
  u16x4 o;
  o.x = f2bf(s.x); o.y = f2bf(s.y); o.z = f2bf(s.z); o.w = f2bf(s.w);
  *reinterpret_cast<u16x4*>(&out[i4]) = o;
}

// ---- gates: r,u = sigmoid(Wgt^T.[z;z1;z2]+b); emit rh(bf16 [+f32]), u(f32) ----
__global__ __launch_bounds__(512) void k_gates(
    const float* __restrict__ x, const float* __restrict__ h,
    const float* __restrict__ Wgt,
    const float* __restrict__ bfv, const float* __restrict__ buv,
    const u16* __restrict__ Z1, const u16* __restrict__ Z2,
    u16* __restrict__ rh_bf, float* __restrict__ rh_f, float* __restrict__ u_f) {
  const int lane = threadIdx.x & 63;
  const int wq = __builtin_amdgcn_readfirstlane(threadIdx.x >> 6);
  const int b = blockIdx.y;
  const int n0 = blockIdx.x * 128 + (lane << 1);
  if (n0 >= NREAL) return;
  const int ob = wq << 4;
  const float* xb = x + (long)b * 32 * NREAL + n0;
  const float* hb = h + (long)b * 64 * NREAL + n0;
  const u16* z1b = Z1 + (long)b * 96 * NPAD + n0;
  const u16* z2b = Z2 + (long)b * 96 * NPAD + n0;

  float a0[16] = {}, a1[16] = {};
#pragma unroll 4
  for (int c = 0; c < 32; ++c) {
    const float2 f = *reinterpret_cast<const float2*>(&xb[(long)c * NREAL]);
#pragma unroll
    for (int oi = 0; oi < 16; ++oi) {
      const float w = Wgt[c * 128 + ob + oi];
      a0[oi] = fmaf(w, f.x, a0[oi]); a1[oi] = fmaf(w, f.y, a1[oi]);
    }
  }
#pragma unroll 4
  for (int c = 0; c < 64; ++c) {
    const float2 f = *reinterpret_cast<const float2*>(&hb[(long)c * NREAL]);
#pragma unroll
    for (int oi = 0; oi < 16; ++oi) {
      const float w = Wgt[(32 + c) * 128 + ob + oi];
      a0[oi] = fmaf(w, f.x, a0[oi]); a1[oi] = fmaf(w, f.y, a1[oi]);
    }
  }
#pragma unroll 4
  for (int c = 0; c < 96; ++c) {
    const unsigned pv = *reinterpret_cast<const unsigned*>(&z1b[(long)c * NPAD]);
    const float f0 = bf2f((u16)(pv & 0xffff)), f1 = bf2f((u16)(pv >> 16));
#pragma unroll
    for (int oi = 0; oi < 16; ++oi) {
      const float w = Wgt[(96 + c) * 128 + ob + oi];
      a0[oi] = fmaf(w, f0, a0[oi]); a1[oi] = fmaf(w, f1, a1[oi]);
    }
  }
#pragma unroll 4
  for (int c = 0; c < 96; ++c) {
    const unsigned pv = *reinterpret_cast<const unsigned*>(&z2b[(long)c * NPAD]);
    const float f0 = bf2f((u16)(pv & 0xffff)), f1 = bf2f((u16)(pv >> 16));
#pragma unroll
    for (int oi = 0; oi < 16; ++oi) {
      const float w = Wgt[(192 + c) * 128 + ob + oi];
      a0[oi] = fmaf(w, f0, a0[oi]); a1[oi] = fmaf(w, f1, a1[oi]);
    }
  }

  if (wq < 4) {
#pragma unroll
    for (int oi = 0; oi < 16; ++oi) {
      const int og = ob + oi;
      const float bb = bfv[og];
      const float r0 = 1.f / (1.f + __expf(-(a0[oi] + bb)));
      const float r1 = 1.f / (1.f + __expf(-(a1[oi] + bb)));
      const float2 hv = *reinterpret_cast<const float2*>(&hb[(long)og * NREAL]);
      const float rh0 = r0 * hv.x, rh1 = r1 * hv.y;
      if (rh_f)
        *reinterpret_cast<float2*>(&rh_f[((long)b * 64 + og) * NREAL + n0]) =
            make_float2(rh0, rh1);
      const unsigned pk = (unsigned)f2bf(rh0) | ((unsigned)f2bf(rh1) << 16);
      *reinterpret_cast<unsigned*>(&rh_bf[((long)b * 64 + og) * NPAD + n0]) = pk;
    }
  } else {
#pragma unroll
    for (int oi = 0; oi < 16; ++oi) {
      const int og = (ob - 64) + oi;
      const float bb = buv[og];
      const float u0 = 1.f / (1.f + __expf(-(a0[oi] + bb)));
      const float u1 = 1.f / (1.f + __expf(-(a1[oi] + bb)));
      *reinterpret_cast<float2*>(&u_f[((long)b * 64 + og) * NREAL + n0]) =
          make_float2(u0, u1);
    }
  }
}

// ---- candidate + output ----
template<bool RHF32>
__global__ __launch_bounds__(512) void k_cand(
    const float* __restrict__ x, const float* __restrict__ h,
    const float* __restrict__ Wct, const float* __restrict__ bcv,
    const u16* __restrict__ Z1, const u16* __restrict__ Z2,
    const u16* __restrict__ Rhb, const u16* __restrict__ Rh1,
    const u16* __restrict__ Rh2,
    const float* __restrict__ rh_f, const float* __restrict__ u_f,
    float* __restrict__ out) {
  const int lane = threadIdx.x & 63;
  const int wq = __builtin_amdgcn_readfirstlane(threadIdx.x >> 6);
  const int ob = (wq & 3) << 4;
  const int n = blockIdx.x * 128 + ((wq >> 2) << 6) + lane;
  const int b = blockIdx.y;
  if (n >= NREAL) return;
  const float* xb = x + (long)b * 32 * NREAL + n;
  const float* hb = h + (long)b * 64 * NREAL + n;
  const u16* z1b = Z1 + (long)b * 96 * NPAD + n;
  const u16* z2b = Z2 + (long)b * 96 * NPAD + n;
  const u16* r1b = Rh1 + (long)b * 64 * NPAD + n;
  const u16* r2b = Rh2 + (long)b * 64 * NPAD + n;
  const float* rfb = rh_f + (long)b * 64 * NREAL + n;
  const u16* rbb = Rhb + (long)b * 64 * NPAD + n;

  float acc[16] = {};
#pragma unroll 4
  for (int c = 0; c < 32; ++c) {
    const float f = xb[(long)c * NREAL];
#pragma unroll
    for (int oi = 0; oi < 16; ++oi)
      acc[oi] = fmaf(Wct[c * 64 + ob + oi], f, acc[oi]);
  }
#pragma unroll 4
  for (int c = 0; c < 64; ++c) {
    const float f = RHF32 ? rfb[(long)c * NREAL] : bf2f(rbb[(long)c * NPAD]);
#pragma unroll
    for (int oi = 0; oi < 16; ++oi)
      acc[oi] = fmaf(Wct[(32 + c) * 64 + ob + oi], f, acc[oi]);
  }
#pragma unroll 4
  for (int c = 0; c < 32; ++c) {
    const float f = bf2f(z1b[(long)c * NPAD]);
#pragma unroll
    for (int oi = 0; oi < 16; ++oi)
      acc[oi] = fmaf(Wct[(96 + c) * 64 + ob + oi], f, acc[oi]);
  }
#pragma unroll 4
  for (int c = 0; c < 64; ++c) {
    const float f = bf2f(r1b[(long)c * NPAD]);
#pragma unroll
    for (int oi = 0; oi < 16; ++oi)
      acc[oi] = fmaf(Wct[(128 + c) * 64 + ob + oi], f, acc[oi]);
  }
#pragma unroll 4
  for (int c = 0; c < 32; ++c) {
    const float f = bf2f(z2b[(long)c * NPAD]);
#pragma unroll
    for (int oi = 0; oi < 16; ++oi)
      acc[oi] = fmaf(Wct[(192 + c) * 64 + ob + oi], f, acc[oi]);
  }
#pragma unroll 4
  for (int c = 0; c < 64; ++c) {
    const float f = bf2f(r2b[(long)c * NPAD]);
#pragma unroll
    for (int oi = 0; oi < 16; ++oi)
      acc[oi] = fmaf(Wct[(224 + c) * 64 + ob + oi], f, acc[oi]);
  }

#pragma unroll
  for (int oi = 0; oi < 16; ++oi) {
    const int og = ob + oi;
    float v = acc[oi] + bcv[og];
    v = fminf(fmaxf(v, -15.f), 15.f);
    const float e2 = __expf(2.f * v);
    const float cv = (e2 - 1.f) / (e2 + 1.f);
    const float u = u_f[((long)b * 64 + og) * NREAL + n];
    out[((long)b * 64 + og) * NREAL + n] = u * hb[(long)og * NREAL] + (1.f - u) * cv;
  }
}

extern "C" void kernel_launch(void* const* d_in, const int* in_sizes, int n_in,
                              void* d_out, int out_size, void* d_ws, size_t ws_size,
                              hipStream_t stream) {
  const float* x   = (const float*)d_in[0];
  const float* h   = (const float*)d_in[1];
  const float* adj = (const float*)d_in[2];
  const float* Wf  = (const float*)d_in[3];
  const float* bf_ = (const float*)d_in[4];
  const float* Wu  = (const float*)d_in[5];
  const float* bu_ = (const float*)d_in[6];
  const float* Wc  = (const float*)d_in[7];
  const float* bc_ = (const float*)d_in[8];
  float* out = (float*)d_out;

  char* p = (char*)d_ws;
  auto alloc = [&](size_t bytes) { char* r = p; p += bytes; return r; };
  u16* adjb = (u16*)alloc((size_t)NPAD * NPAD * 2);
  u16* Zg   = (u16*)alloc((size_t)1536 * NPAD * 2);       // Rhb aliases Zg
  u16* Rhb  = Zg;
  u16* Z1   = (u16*)alloc((size_t)1536 * NPAD * 2);
  u16* Z2   = (u16*)alloc((size_t)1536 * NPAD * 2);
  u16* Rh1  = (u16*)alloc((size_t)1024 * NPAD * 2);
  u16* Rh2  = (u16*)alloc((size_t)1024 * NPAD * 2);
  float* uf = (float*)alloc((size_t)16 * 64 * NREAL * 4);
  float* Wgt = (float*)alloc(288 * 128 * 4);
  float* Wct = (float*)alloc(288 * 64 * 4);
  const size_t RHFB = (size_t)16 * 64 * NREAL * 4;
  size_t used = (size_t)(p - (char*)d_ws);
  float* rhf = nullptr;
  if (ws_size >= used + RHFB) rhf = (float*)alloc(RHFB);
  used = (size_t)(p - (char*)d_ws);

  const size_t PZ2 = (size_t)2 * 1536 * NPAD * 4;
  const size_t PR4 = (size_t)4 * 1024 * NPAD * 4;
  int sZ = 1, sR = 1;
  float* P = nullptr;
  if (ws_size >= used + PR4)      { P = (float*)alloc(PR4); sZ = 2; sR = 4; }
  else if (ws_size >= used + PZ2) { P = (float*)alloc(PZ2); sZ = 2; sR = 2; }

  auto gemmZ = [&](const u16* Ax, const u16* Bx, u16* Cb) {   // M=1536, 8-phase
    const long ce = (long)1536 * NPAD;
    if (sZ == 2) {
      k_gemm8p<true><<<dim3(16, 6, 2), 512, 0, stream>>>(Ax, Bx, P, 32, ce);
      k_combine<2><<<dim3(1536 * 4), 256, 0, stream>>>(P, ce, Cb);
    } else {
      k_gemm8p<false><<<dim3(16, 6, 1), 512, 0, stream>>>(Ax, Bx, Cb, 64, ce);
    }
  };
  auto gemmR = [&](const u16* Ax, const u16* Bx, u16* Cb) {   // M=1024, 2-phase
    const long ce = (long)1024 * NPAD;
    if (sR == 4) {
      k_gemm256<true><<<dim3(16, 4, 4), 512, 0, stream>>>(Ax, Bx, P, 16, ce);
      k_combine<4><<<dim3(1024 * 4), 256, 0, stream>>>(P, ce, Cb);
    } else if (sR == 2) {
      k_gemm256<true><<<dim3(16, 4, 2), 512, 0, stream>>>(Ax, Bx, P, 32, ce);
      k_combine<2><<<dim3(1024 * 4), 256, 0, stream>>>(P, ce, Cb);
    } else {
      k_gemm256<false><<<dim3(16, 4, 1), 512, 0, stream>>>(Ax, Bx, Cb, 64, ce);
    }
  };

  k_pack_adj<<<dim3(NPAD * (NPAD / 4) / 256), 256, 0, stream>>>(adj, adjb);
  k_pack_zg <<<dim3(1536 * (NPAD / 4) / 256), 256, 0, stream>>>(x, h, Zg);
  k_pack_w  <<<dim3(144), 256, 0, stream>>>(Wf, Wu, Wc, Wgt, Wct);
  gemmZ(Zg, adjb, Z1);                                        // Z1 = Zg A^T
  gemmZ(Z1, adjb, Z2);                                        // Z2 = Z1 A^T
  k_gates<<<dim3(32, 16), 512, 0, stream>>>(x, h, Wgt, bf_, bu_, Z1, Z2,
                                            Rhb, rhf, uf);
  gemmR(Rhb, adjb, Rh1);                                      // Rh1 = rh A^T
  gemmR(Rh1, adjb, Rh2);                                      // Rh2 = Rh1 A^T
  if (rhf)
    k_cand<true><<<dim3(32, 16), 512, 0, stream>>>(x, h, Wct, bc_, Z1, Z2, Rhb,
                                                   Rh1, Rh2, rhf, uf, out);
  else
    k_cand<false><<<dim3(32, 16), 512, 0, stream>>>(x, h, Wct, bc_, Z1, Z2, Rhb,
                                                    Rh1, Rh2, rhf, uf, out);
}

// Round 7
// 472.455 us; speedup vs baseline: 1.1528x; 1.0213x over previous
//
#include <hip/hip_runtime.h>
#include <cstdint>

// GCGRU cell, restructured:
//   Zg = [x;h] (1536x4000)  -> Z1 = Zg A^T, Z2 = Z1 A^T      (shared by r,u)
//   gates: r,u = sigmoid(W{f,u} . [Zg;Z1;Z2] + b)            (fp32 conv)
//   rh = r*h (1024x4000)    -> Rh1 = rh A^T, Rh2 = Rh1 A^T
//   cand: c = tanh(Wc . [x,rh, Ax,Arh, A2x,A2rh] + bc);  out = u h + (1-u) c
//
// Round-7: round-6 arithmetic showed the GEMM inner loop is already at
// reference per-block rate (~7 TF/block); loss = grid quantization (Z: 384
// blocks @ 1/CU = 1.5 rounds). Fix: sZ=4 (K-chunk 1024, job grain halves ->
// makespan 2x19us not 2x38us), sR=4 (grid 256 = exactly 1 round), bf16
// split-K partials (P 50MB, combine traffic ~= old NC2-f32). One GEMM kernel
// (8-phase skeleton; A/B vs 2-phase was null) for all 4 GEMMs.

#define NREAL 4000
#define NPAD  4096

typedef unsigned short u16;
typedef __attribute__((ext_vector_type(8))) short short8;
typedef __attribute__((ext_vector_type(4))) float f32x4;
typedef __attribute__((ext_vector_type(4))) unsigned short u16x4;
typedef __attribute__((ext_vector_type(8))) unsigned short u16x8;

__device__ __forceinline__ u16 f2bf(float f) {
  unsigned u = __builtin_bit_cast(unsigned, f);
  return (u16)((u + 0x7FFFu + ((u >> 16) & 1u)) >> 16);
}
__device__ __forceinline__ float bf2f(u16 b) {
  unsigned u = ((unsigned)b) << 16;
  return __builtin_bit_cast(float, u);
}

// ---- adj f32 [4000][4000] -> bf16 [4096][4096], zero-padded ----
__global__ __launch_bounds__(256) void k_pack_adj(const float* __restrict__ adj,
                                                  u16* __restrict__ out) {
  const int idx = blockIdx.x * 256 + threadIdx.x;
  const int m = idx >> 10;
  const int n0 = (idx & 1023) << 2;
  u16x4 o;
  if (m < NREAL && n0 < NREAL) {
    const float4 v = *reinterpret_cast<const float4*>(&adj[(long)m * NREAL + n0]);
    o.x = f2bf(v.x); o.y = f2bf(v.y); o.z = f2bf(v.z); o.w = f2bf(v.w);
  } else {
    o.x = 0; o.y = 0; o.z = 0; o.w = 0;
  }
  *reinterpret_cast<u16x4*>(&out[(long)m * NPAD + n0]) = o;
}

// ---- Zg bf16 [1536][4096] = rows (b*96+c): c<32 -> x, else h ----
__global__ __launch_bounds__(256) void k_pack_zg(const float* __restrict__ x,
                                                 const float* __restrict__ h,
                                                 u16* __restrict__ zg) {
  const int idx = blockIdx.x * 256 + threadIdx.x;
  const int row = idx >> 10;
  const int n0 = (idx & 1023) << 2;
  const int b = row / 96, c = row % 96;
  const float* src = (c < 32) ? &x[((long)b * 32 + c) * NREAL]
                              : &h[((long)b * 64 + (c - 32)) * NREAL];
  u16x4 o;
  if (n0 < NREAL) {
    const float4 v = *reinterpret_cast<const float4*>(&src[n0]);
    o.x = f2bf(v.x); o.y = f2bf(v.y); o.z = f2bf(v.z); o.w = f2bf(v.w);
  } else {
    o.x = 0; o.y = 0; o.z = 0; o.w = 0;
  }
  *reinterpret_cast<u16x4*>(&zg[(long)row * NPAD + n0]) = o;
}

// ---- W transpose pack: Wgt[c][128] = [Wf;Wu]^T, Wct[c][64] = Wc^T ----
__global__ __launch_bounds__(256) void k_pack_w(const float* __restrict__ Wf,
                                                const float* __restrict__ Wu,
                                                const float* __restrict__ Wc,
                                                float* __restrict__ Wgt,
                                                float* __restrict__ Wct) {
  const int idx = blockIdx.x * 256 + threadIdx.x;
  if (idx < 288 * 128) {
    const int c = idx >> 7, o = idx & 127;
    Wgt[idx] = (o < 64) ? Wf[o * 288 + c] : Wu[(o - 64) * 288 + c];
  }
  if (idx < 288 * 64) {
    const int c = idx >> 6, o = idx & 63;
    Wct[idx] = Wc[o * 288 + c];
  }
}

#define GLDS(dst, src)                                                         \
  __builtin_amdgcn_global_load_lds(                                            \
      (const __attribute__((address_space(1))) void*)(src),                    \
      (__attribute__((address_space(3))) void*)(dst), 16, 0, 0)

// ---- NT bf16 GEMM, 256x256/BK=64/8-wave, 4-phase dual-barrier skeleton ----
// C[i][m] = sum_n A[i][n]*B[m][n]; writes bf16 (final or split-K partial at
// z*chunkElems). Phase p: MFMA quadrant mi{2p,2p+1}x4ni x K=64; stages one
// half-tile of t+1 (p0:B01,p1:B23,p2:A02,p3:A13); counted vmcnt(4)@p1 /
// vmcnt(2)@p3 (never 0 mid-loop). T2 swizzle: slot s of row r holds kgrp
// s^(r&7); pre-swizzled global source, XOR'd ds_read addr.
__global__ __launch_bounds__(512) void k_gemm8p(const u16* __restrict__ A,
                                                const u16* __restrict__ B,
                                                u16* __restrict__ Cout,
                                                int ktPerChunk, long chunkElems) {
  __shared__ __align__(16) u16 As[2][256 * 64];
  __shared__ __align__(16) u16 Bs[2][256 * 64];
  const int tid = threadIdx.x;
  const int lane = tid & 63;
  const int wv = tid >> 6;
  const int wm = wv >> 2;           // 0..1  M-half
  const int wn = wv & 3;            // 0..3  N-quarter

  const int srow = tid >> 3;
  const int jlog = (tid & 7) ^ (srow & 7);
  const long kt0 = (long)blockIdx.z * ktPerChunk * 64;
  const u16* aB = A + (long)(blockIdx.y * 256 + srow) * NPAD + kt0 + jlog * 8;
  const u16* bB = B + (long)(blockIdx.x * 256 + srow) * NPAD + kt0 + jlog * 8;
  const int ldst = tid * 8;

  const int fr = lane & 15;
  const int swz = (fr & 7) << 4;
  const int kb0 = (((lane >> 4) << 4)) ^ swz;
  const int kb1 = (64 + ((lane >> 4) << 4)) ^ swz;

  f32x4 acc[8][4] = {};
  const int T = ktPerChunk;

  // prologue: tile 0 fully staged, one-time full drain
  GLDS(&Bs[0][0 + ldst],     bB);
  GLDS(&Bs[0][4096 + ldst],  bB + 64L * NPAD);
  GLDS(&Bs[0][8192 + ldst],  bB + 128L * NPAD);
  GLDS(&Bs[0][12288 + ldst], bB + 192L * NPAD);
  GLDS(&As[0][0 + ldst],     aB);
  GLDS(&As[0][8192 + ldst],  aB + 128L * NPAD);
  GLDS(&As[0][4096 + ldst],  aB + 64L * NPAD);
  GLDS(&As[0][12288 + ldst], aB + 192L * NPAD);
  asm volatile("s_waitcnt vmcnt(0)" ::: "memory");
  __builtin_amdgcn_s_barrier();

  for (int t = 0; t < T; ++t) {
    const int bs = t & 1;
    const char* Ab = (const char*)&As[bs][0];
    const char* Bb = (const char*)&Bs[bs][0];
    u16* An = &As[bs ^ 1][0];
    u16* Bn = &Bs[bs ^ 1][0];
    const bool more = (t + 1 < T);
    const long ko = (long)(t + 1) * 64;
    short8 bv[4][2];
#pragma unroll
    for (int p = 0; p < 4; ++p) {
      // --- ds-load register subtile ---
      if (p == 0) {
#pragma unroll
        for (int ni = 0; ni < 4; ++ni) {
          const int brow = (wn << 6) + (ni << 4) + fr;
          bv[ni][0] = *(const short8*)(Bb + brow * 128 + kb0);
          bv[ni][1] = *(const short8*)(Bb + brow * 128 + kb1);
        }
      }
      short8 av[2][2];
#pragma unroll
      for (int q = 0; q < 2; ++q) {
        const int arow = (wm << 7) + ((2 * p + q) << 4) + fr;
        av[q][0] = *(const short8*)(Ab + arow * 128 + kb0);
        av[q][1] = *(const short8*)(Ab + arow * 128 + kb1);
      }
      // --- stage 1 half-tile of t+1 ---
      if (more) {
        if (p == 0) { GLDS(Bn + ldst, bB + ko);
                      GLDS(Bn + 4096 + ldst, bB + 64L * NPAD + ko); }
        if (p == 1) { GLDS(Bn + 8192 + ldst, bB + 128L * NPAD + ko);
                      GLDS(Bn + 12288 + ldst, bB + 192L * NPAD + ko); }
        if (p == 2) { GLDS(An + ldst, aB + ko);
                      GLDS(An + 8192 + ldst, aB + 128L * NPAD + ko); }
        if (p == 3) { GLDS(An + 4096 + ldst, aB + 64L * NPAD + ko);
                      GLDS(An + 12288 + ldst, aB + 192L * NPAD + ko); }
      }
      if (p == 0) asm volatile("s_waitcnt lgkmcnt(8)" ::: "memory");
      __builtin_amdgcn_s_barrier();
      asm volatile("s_waitcnt lgkmcnt(0)" ::: "memory");
      __builtin_amdgcn_sched_barrier(0);     // rule 18: pin MFMA below the wait
      __builtin_amdgcn_s_setprio(1);
#pragma unroll
      for (int q = 0; q < 2; ++q)
#pragma unroll
        for (int ni = 0; ni < 4; ++ni) {
          acc[2 * p + q][ni] = __builtin_amdgcn_mfma_f32_16x16x32_bf16(
              av[q][0], bv[ni][0], acc[2 * p + q][ni], 0, 0, 0);
          acc[2 * p + q][ni] = __builtin_amdgcn_mfma_f32_16x16x32_bf16(
              av[q][1], bv[ni][1], acc[2 * p + q][ni], 0, 0, 0);
        }
      __builtin_amdgcn_s_setprio(0);
      if (p == 1) {                  // A-chunks{1,3}(t) must land for p2/p3
        if (more) asm volatile("s_waitcnt vmcnt(4)" ::: "memory");
        else      asm volatile("s_waitcnt vmcnt(0)" ::: "memory");
      }
      if (p == 3 && more)            // B(t+1)+A02(t+1) landed; A13(t+1) flies
        asm volatile("s_waitcnt vmcnt(2)" ::: "memory");
      __builtin_amdgcn_s_barrier();
    }
  }

  // C/D layout (m89-verified): col = lane&15, row = (lane>>4)*4 + q
  u16* C = Cout + (long)blockIdx.z * chunkElems;
  const int rb = blockIdx.y * 256 + (wm << 7) + ((lane >> 4) << 2);
  const int cb = blockIdx.x * 256 + (wn << 6) + fr;
#pragma unroll
  for (int mi = 0; mi < 8; ++mi)
#pragma unroll
    for (int ni = 0; ni < 4; ++ni)
#pragma unroll
      for (int q = 0; q < 4; ++q)
        C[(long)(rb + (mi << 4) + q) * NPAD + cb + (ni << 4)] = f2bf(acc[mi][ni][q]);
}

// ---- sum NC bf16 partial chunks -> bf16 (8 elems/thread) ----
template<int NC>
__global__ __launch_bounds__(256) void k_combine_bf(const u16* __restrict__ P,
                                                    long chunkElems,
                                                    u16* __restrict__ out) {
  const long i8 = ((long)blockIdx.x * 256 + threadIdx.x) * 8;
  float s[8];
  {
    const u16x8 v = *reinterpret_cast<const u16x8*>(&P[i8]);
#pragma unroll
    for (int j = 0; j < 8; ++j) s[j] = bf2f(v[j]);
  }
#pragma unroll
  for (int c = 1; c < NC; ++c) {
    const u16x8 v = *reinterpret_cast<const u16x8*>(&P[(long)c * chunkElems + i8]);
#pragma unroll
    for (int j = 0; j < 8; ++j) s[j] += bf2f(v[j]);
  }
  u16x8 o;
#pragma unroll
  for (int j = 0; j < 8; ++j) o[j] = f2bf(s[j]);
  *reinterpret_cast<u16x8*>(&out[i8]) = o;
}

// ---- gates: r,u = sigmoid(Wgt^T.[z;z1;z2]+b); emit rh(bf16 [+f32]), u(f32) ----
__global__ __launch_bounds__(512) void k_gates(
    const float* __restrict__ x, const float* __restrict__ h,
    const float* __restrict__ Wgt,
    const float* __restrict__ bfv, const float* __restrict__ buv,
    const u16* __restrict__ Z1, const u16* __restrict__ Z2,
    u16* __restrict__ rh_bf, float* __restrict__ rh_f, float* __restrict__ u_f) {
  const int lane = threadIdx.x & 63;
  const int wq = __builtin_amdgcn_readfirstlane(threadIdx.x >> 6);
  const int b = blockIdx.y;
  const int n0 = blockIdx.x * 128 + (lane << 1);
  if (n0 >= NREAL) return;
  const int ob = wq << 4;
  const float* xb = x + (long)b * 32 * NREAL + n0;
  const float* hb = h + (long)b * 64 * NREAL + n0;
  const u16* z1b = Z1 + (long)b * 96 * NPAD + n0;
  const u16* z2b = Z2 + (long)b * 96 * NPAD + n0;

  float a0[16] = {}, a1[16] = {};
#pragma unroll 4
  for (int c = 0; c < 32; ++c) {
    const float2 f = *reinterpret_cast<const float2*>(&xb[(long)c * NREAL]);
#pragma unroll
    for (int oi = 0; oi < 16; ++oi) {
      const float w = Wgt[c * 128 + ob + oi];
      a0[oi] = fmaf(w, f.x, a0[oi]); a1[oi] = fmaf(w, f.y, a1[oi]);
    }
  }
#pragma unroll 4
  for (int c = 0; c < 64; ++c) {
    const float2 f = *reinterpret_cast<const float2*>(&hb[(long)c * NREAL]);
#pragma unroll
    for (int oi = 0; oi < 16; ++oi) {
      const float w = Wgt[(32 + c) * 128 + ob + oi];
      a0[oi] = fmaf(w, f.x, a0[oi]); a1[oi] = fmaf(w, f.y, a1[oi]);
    }
  }
#pragma unroll 4
  for (int c = 0; c < 96; ++c) {
    const unsigned pv = *reinterpret_cast<const unsigned*>(&z1b[(long)c * NPAD]);
    const float f0 = bf2f((u16)(pv & 0xffff)), f1 = bf2f((u16)(pv >> 16));
#pragma unroll
    for (int oi = 0; oi < 16; ++oi) {
      const float w = Wgt[(96 + c) * 128 + ob + oi];
      a0[oi] = fmaf(w, f0, a0[oi]); a1[oi] = fmaf(w, f1, a1[oi]);
    }
  }
#pragma unroll 4
  for (int c = 0; c < 96; ++c) {
    const unsigned pv = *reinterpret_cast<const unsigned*>(&z2b[(long)c * NPAD]);
    const float f0 = bf2f((u16)(pv & 0xffff)), f1 = bf2f((u16)(pv >> 16));
#pragma unroll
    for (int oi = 0; oi < 16; ++oi) {
      const float w = Wgt[(192 + c) * 128 + ob + oi];
      a0[oi] = fmaf(w, f0, a0[oi]); a1[oi] = fmaf(w, f1, a1[oi]);
    }
  }

  if (wq < 4) {
#pragma unroll
    for (int oi = 0; oi < 16; ++oi) {
      const int og = ob + oi;
      const float bb = bfv[og];
      const float r0 = 1.f / (1.f + __expf(-(a0[oi] + bb)));
      const float r1 = 1.f / (1.f + __expf(-(a1[oi] + bb)));
      const float2 hv = *reinterpret_cast<const float2*>(&hb[(long)og * NREAL]);
      const float rh0 = r0 * hv.x, rh1 = r1 * hv.y;
      if (rh_f)
        *reinterpret_cast<float2*>(&rh_f[((long)b * 64 + og) * NREAL + n0]) =
            make_float2(rh0, rh1);
      const unsigned pk = (unsigned)f2bf(rh0) | ((unsigned)f2bf(rh1) << 16);
      *reinterpret_cast<unsigned*>(&rh_bf[((long)b * 64 + og) * NPAD + n0]) = pk;
    }
  } else {
#pragma unroll
    for (int oi = 0; oi < 16; ++oi) {
      const int og = (ob - 64) + oi;
      const float bb = buv[og];
      const float u0 = 1.f / (1.f + __expf(-(a0[oi] + bb)));
      const float u1 = 1.f / (1.f + __expf(-(a1[oi] + bb)));
      *reinterpret_cast<float2*>(&u_f[((long)b * 64 + og) * NREAL + n0]) =
          make_float2(u0, u1);
    }
  }
}

// ---- candidate + output ----
template<bool RHF32>
__global__ __launch_bounds__(512) void k_cand(
    const float* __restrict__ x, const float* __restrict__ h,
    const float* __restrict__ Wct, const float* __restrict__ bcv,
    const u16* __restrict__ Z1, const u16* __restrict__ Z2,
    const u16* __restrict__ Rhb, const u16* __restrict__ Rh1,
    const u16* __restrict__ Rh2,
    const float* __restrict__ rh_f, const float* __restrict__ u_f,
    float* __restrict__ out) {
  const int lane = threadIdx.x & 63;
  const int wq = __builtin_amdgcn_readfirstlane(threadIdx.x >> 6);
  const int ob = (wq & 3) << 4;
  const int n = blockIdx.x * 128 + ((wq >> 2) << 6) + lane;
  const int b = blockIdx.y;
  if (n >= NREAL) return;
  const float* xb = x + (long)b * 32 * NREAL + n;
  const float* hb = h + (long)b * 64 * NREAL + n;
  const u16* z1b = Z1 + (long)b * 96 * NPAD + n;
  const u16* z2b = Z2 + (long)b * 96 * NPAD + n;
  const u16* r1b = Rh1 + (long)b * 64 * NPAD + n;
  const u16* r2b = Rh2 + (long)b * 64 * NPAD + n;
  const float* rfb = rh_f + (long)b * 64 * NREAL + n;
  const u16* rbb = Rhb + (long)b * 64 * NPAD + n;

  float acc[16] = {};
#pragma unroll 4
  for (int c = 0; c < 32; ++c) {
    const float f = xb[(long)c * NREAL];
#pragma unroll
    for (int oi = 0; oi < 16; ++oi)
      acc[oi] = fmaf(Wct[c * 64 + ob + oi], f, acc[oi]);
  }
#pragma unroll 4
  for (int c = 0; c < 64; ++c) {
    const float f = RHF32 ? rfb[(long)c * NREAL] : bf2f(rbb[(long)c * NPAD]);
#pragma unroll
    for (int oi = 0; oi < 16; ++oi)
      acc[oi] = fmaf(Wct[(32 + c) * 64 + ob + oi], f, acc[oi]);
  }
#pragma unroll 4
  for (int c = 0; c < 32; ++c) {
    const float f = bf2f(z1b[(long)c * NPAD]);
#pragma unroll
    for (int oi = 0; oi < 16; ++oi)
      acc[oi] = fmaf(Wct[(96 + c) * 64 + ob + oi], f, acc[oi]);
  }
#pragma unroll 4
  for (int c = 0; c < 64; ++c) {
    const float f = bf2f(r1b[(long)c * NPAD]);
#pragma unroll
    for (int oi = 0; oi < 16; ++oi)
      acc[oi] = fmaf(Wct[(128 + c) * 64 + ob + oi], f, acc[oi]);
  }
#pragma unroll 4
  for (int c = 0; c < 32; ++c) {
    const float f = bf2f(z2b[(long)c * NPAD]);
#pragma unroll
    for (int oi = 0; oi < 16; ++oi)
      acc[oi] = fmaf(Wct[(192 + c) * 64 + ob + oi], f, acc[oi]);
  }
#pragma unroll 4
  for (int c = 0; c < 64; ++c) {
    const float f = bf2f(r2b[(long)c * NPAD]);
#pragma unroll
    for (int oi = 0; oi < 16; ++oi)
      acc[oi] = fmaf(Wct[(224 + c) * 64 + ob + oi], f, acc[oi]);
  }

#pragma unroll
  for (int oi = 0; oi < 16; ++oi) {
    const int og = ob + oi;
    float v = acc[oi] + bcv[og];
    v = fminf(fmaxf(v, -15.f), 15.f);
    const float e2 = __expf(2.f * v);
    const float cv = (e2 - 1.f) / (e2 + 1.f);
    const float u = u_f[((long)b * 64 + og) * NREAL + n];
    out[((long)b * 64 + og) * NREAL + n] = u * hb[(long)og * NREAL] + (1.f - u) * cv;
  }
}

extern "C" void kernel_launch(void* const* d_in, const int* in_sizes, int n_in,
                              void* d_out, int out_size, void* d_ws, size_t ws_size,
                              hipStream_t stream) {
  const float* x   = (const float*)d_in[0];
  const float* h   = (const float*)d_in[1];
  const float* adj = (const float*)d_in[2];
  const float* Wf  = (const float*)d_in[3];
  const float* bf_ = (const float*)d_in[4];
  const float* Wu  = (const float*)d_in[5];
  const float* bu_ = (const float*)d_in[6];
  const float* Wc  = (const float*)d_in[7];
  const float* bc_ = (const float*)d_in[8];
  float* out = (float*)d_out;

  char* p = (char*)d_ws;
  auto alloc = [&](size_t bytes) { char* r = p; p += bytes; return r; };
  u16* adjb = (u16*)alloc((size_t)NPAD * NPAD * 2);
  u16* Zg   = (u16*)alloc((size_t)1536 * NPAD * 2);       // Rhb aliases Zg
  u16* Rhb  = Zg;
  u16* Z1   = (u16*)alloc((size_t)1536 * NPAD * 2);
  u16* Z2   = (u16*)alloc((size_t)1536 * NPAD * 2);
  u16* Rh1  = (u16*)alloc((size_t)1024 * NPAD * 2);
  u16* Rh2  = (u16*)alloc((size_t)1024 * NPAD * 2);
  float* uf = (float*)alloc((size_t)16 * 64 * NREAL * 4);
  float* Wgt = (float*)alloc(288 * 128 * 4);
  float* Wct = (float*)alloc(288 * 64 * 4);
  const size_t RHFB = (size_t)16 * 64 * NREAL * 4;
  size_t used = (size_t)(p - (char*)d_ws);
  float* rhf = nullptr;
  if (ws_size >= used + RHFB) rhf = (float*)alloc(RHFB);
  used = (size_t)(p - (char*)d_ws);

  // split-K bf16 partial buffer: 4 chunks of the largest output (Z: 12.58MB)
  const size_t PB4 = (size_t)4 * 1536 * NPAD * 2;   // 50.33 MB
  const size_t PB2 = (size_t)2 * 1536 * NPAD * 2;   // 25.17 MB
  int sK = 1;
  u16* Pb = nullptr;
  if (ws_size >= used + PB4)      { sK = 4; Pb = (u16*)alloc(PB4); }
  else if (ws_size >= used + PB2) { sK = 2; Pb = (u16*)alloc(PB2); }

  auto gemm = [&](const u16* Ax, const u16* Bx, u16* Cb, int M) {
    const long ce = (long)M * NPAD;
    const int mt = M / 256;
    if (sK == 4) {
      k_gemm8p<<<dim3(16, mt, 4), 512, 0, stream>>>(Ax, Bx, Pb, 16, ce);
      k_combine_bf<4><<<dim3((int)(ce / 2048)), 256, 0, stream>>>(Pb, ce, Cb);
    } else if (sK == 2) {
      k_gemm8p<<<dim3(16, mt, 2), 512, 0, stream>>>(Ax, Bx, Pb, 32, ce);
      k_combine_bf<2><<<dim3((int)(ce / 2048)), 256, 0, stream>>>(Pb, ce, Cb);
    } else {
      k_gemm8p<<<dim3(16, mt, 1), 512, 0, stream>>>(Ax, Bx, Cb, 64, ce);
    }
  };

  k_pack_adj<<<dim3(NPAD * (NPAD / 4) / 256), 256, 0, stream>>>(adj, adjb);
  k_pack_zg <<<dim3(1536 * (NPAD / 4) / 256), 256, 0, stream>>>(x, h, Zg);
  k_pack_w  <<<dim3(144), 256, 0, stream>>>(Wf, Wu, Wc, Wgt, Wct);
  gemm(Zg, adjb, Z1, 1536);                                   // Z1 = Zg A^T
  gemm(Z1, adjb, Z2, 1536);                                   // Z2 = Z1 A^T
  k_gates<<<dim3(32, 16), 512, 0, stream>>>(x, h, Wgt, bf_, bu_, Z1, Z2,
                                            Rhb, rhf, uf);
  gemm(Rhb, adjb, Rh1, 1024);                                 // Rh1 = rh A^T
  gemm(Rh1, adjb, Rh2, 1024);                                 // Rh2 = Rh1 A^T
  if (rhf)
    k_cand<true><<<dim3(32, 16), 512, 0, stream>>>(x, h, Wct, bc_, Z1, Z2, Rhb,
                                                   Rh1, Rh2, rhf, uf, out);
  else
    k_cand<false><<<dim3(32, 16), 512, 0, stream>>>(x, h, Wct, bc_, Z1, Z2, Rhb,
                                                    Rh1, Rh2, rhf, uf, out);
}